// Round 2
// 540.640 us; speedup vs baseline: 1.7511x; 1.7511x over previous
//
#include <hip/hip_runtime.h>
#include <hip/hip_bf16.h>

typedef __hip_bfloat16 bf16;
typedef float f32x4 __attribute__((ext_vector_type(4)));
typedef short s16x8 __attribute__((ext_vector_type(8)));

static __device__ __forceinline__ float b2f(bf16 h) { return __bfloat162float(h); }
static __device__ __forceinline__ float us2f(unsigned short u) {
    union { unsigned short u; bf16 h; } cv; cv.u = u; return __bfloat162float(cv.h);
}
static __device__ __forceinline__ unsigned short f2us(float f) {
    __hip_bfloat16 h = __float2bfloat16(f);
    union { __hip_bfloat16 h; unsigned short u; } cv; cv.h = h; return cv.u;
}

// ws layout (ushort elements). Split-bf16 planes: x = hi + lo (each bf16).
//   qT hi: [64 b][1024 n][32 o]   at 0          (2,097,152)
//   qT lo:                        at 2,097,152
//   kT hi: [16 ib][1024 m][32 o]  at 4,194,304  (  524,288)
//   kT lo:                        at 4,718,592
//   v  hi: [16 ib][64 d][1024 m]  at 5,242,880  (1,048,576)
//   v  lo:                        at 6,291,456
//   flags (int[4])                at byte 14,680,064
#define QHI 0
#define QLO 2097152
#define KHI 4194304
#define KLO 4718592
#define VHI 5242880
#define VLO 6291456
#define FLG_BYTE 14680064

static __device__ __forceinline__ f32x4 mfma16(s16x8 a, s16x8 b, f32x4 c) {
    return __builtin_amdgcn_mfma_f32_16x16x32_bf16(a, b, c, 0, 0, 0);
}

// ---------------- Kernel 0: dtype detection (unchanged) ----------------
__global__ __launch_bounds__(256) void detect_kernel(
    const void* inp, const void* dyn, const void* wq, int* flags)
{
    __shared__ int bad;
    if (threadIdx.x == 0) bad = 0;
    __syncthreads();
    const void* bufs[3] = { inp, dyn, wq };
    const int nscan[3] = { 2048, 2048, 1024 };
    const int b = blockIdx.x;
    const unsigned short* u = (const unsigned short*)bufs[b];
    int myBad = 0;
    for (int i = threadIdx.x; i < nscan[b]; i += 256) {
        float x = us2f(u[i * 2]);
        if (!(x > -1e4f && x < 1e4f)) myBad++;
    }
    atomicAdd(&bad, myBad);
    __syncthreads();
    if (threadIdx.x == 0) flags[b] = (bad >= 4) ? 1 : 0;
}

// ---------------- Kernel 1: projections -> split-bf16 transposed planes ----------------
// blocks 0..63   : k+v for 16 xin-batches (4 blocks of 256 n each)
// blocks 64..319 : q for 64 batches (4 blocks of 256 n each)
__global__ __launch_bounds__(256) void proj_kernel(
    const void* __restrict__ inputs, const void* __restrict__ dyn,
    const void* __restrict__ wq, const void* __restrict__ bq,
    const void* __restrict__ wk, const void* __restrict__ bk,
    const void* __restrict__ wv, const void* __restrict__ bv,
    unsigned short* __restrict__ wsu, const int* __restrict__ flags)
{
    __shared__ float sW[6240];      // wk(2048)+wv(4096)+bk(32)+bv(64)  OR wq(2048)+bq(32)
    const int t = threadIdx.x;
    const int blk = blockIdx.x;
    const int fin  = flags[0];
    const int fdyn = flags[1];
    const int fw   = flags[2];
    unsigned int* ws32 = (unsigned int*)wsu;

    if (blk < 64) {
        const int ib = blk >> 2;
        const int n = ((blk & 3) << 8) + t;
        if (fw) {
            const float* wkf = (const float*)wk; const float* wvf = (const float*)wv;
            const float* bkf = (const float*)bk; const float* bvf = (const float*)bv;
            for (int i = t; i < 2048; i += 256) sW[i] = wkf[i];
            for (int i = t; i < 4096; i += 256) sW[2048 + i] = wvf[i];
            if (t < 32) sW[6144 + t] = bkf[t];
            else if (t >= 64 && t < 128) sW[6176 + (t - 64)] = bvf[t - 64];
        } else {
            const bf16* wkb = (const bf16*)wk; const bf16* wvb = (const bf16*)wv;
            const bf16* bkb = (const bf16*)bk; const bf16* bvb = (const bf16*)bv;
            for (int i = t; i < 2048; i += 256) sW[i] = b2f(wkb[i]);
            for (int i = t; i < 4096; i += 256) sW[2048 + i] = b2f(wvb[i]);
            if (t < 32) sW[6144 + t] = b2f(bkb[t]);
            else if (t >= 64 && t < 128) sW[6176 + (t - 64)] = b2f(bvb[t - 64]);
        }
        __syncthreads();

        float ak[32], av[64];
        #pragma unroll
        for (int o = 0; o < 32; o++) ak[o] = sW[6144 + o];
        #pragma unroll
        for (int d = 0; d < 64; d++) av[d] = sW[6176 + d];

        const int xoff = ib * 65536 + n;
        if (fin) {
            const float* xp = (const float*)inputs + xoff;
            for (int c = 0; c < 64; c++) {
                float x = xp[c << 10];
                #pragma unroll
                for (int o = 0; o < 32; o++) ak[o] = fmaf(sW[(o << 6) + c], x, ak[o]);
                #pragma unroll
                for (int d = 0; d < 64; d++) av[d] = fmaf(sW[2048 + (d << 6) + c], x, av[d]);
            }
        } else {
            const bf16* xp = (const bf16*)inputs + xoff;
            for (int c = 0; c < 64; c++) {
                float x = b2f(xp[c << 10]);
                #pragma unroll
                for (int o = 0; o < 32; o++) ak[o] = fmaf(sW[(o << 6) + c], x, ak[o]);
                #pragma unroll
                for (int d = 0; d < 64; d++) av[d] = fmaf(sW[2048 + (d << 6) + c], x, av[d]);
            }
        }

        // kT[ib][n][o] split-bf16: per-thread contiguous 64B row per plane
        {
            unsigned short hs[32], ls[32];
            #pragma unroll
            for (int o = 0; o < 32; o++) {
                unsigned short h = f2us(ak[o]);
                hs[o] = h;
                ls[o] = f2us(ak[o] - us2f(h));
            }
            unsigned int* ph = ws32 + (KHI >> 1) + ib * 16384 + n * 16;
            unsigned int* pl = ws32 + (KLO >> 1) + ib * 16384 + n * 16;
            #pragma unroll
            for (int j = 0; j < 4; j++) {
                uint4 a, c;
                a.x = (unsigned)hs[j*8+0] | ((unsigned)hs[j*8+1] << 16);
                a.y = (unsigned)hs[j*8+2] | ((unsigned)hs[j*8+3] << 16);
                a.z = (unsigned)hs[j*8+4] | ((unsigned)hs[j*8+5] << 16);
                a.w = (unsigned)hs[j*8+6] | ((unsigned)hs[j*8+7] << 16);
                c.x = (unsigned)ls[j*8+0] | ((unsigned)ls[j*8+1] << 16);
                c.y = (unsigned)ls[j*8+2] | ((unsigned)ls[j*8+3] << 16);
                c.z = (unsigned)ls[j*8+4] | ((unsigned)ls[j*8+5] << 16);
                c.w = (unsigned)ls[j*8+6] | ((unsigned)ls[j*8+7] << 16);
                *reinterpret_cast<uint4*>(ph + j * 4) = a;
                *reinterpret_cast<uint4*>(pl + j * 4) = c;
            }
        }
        // v[ib][d][m=n] split-bf16: ushort stores, lanes contiguous in n -> coalesced
        {
            unsigned short* vh = wsu + VHI + ib * 65536 + n;
            unsigned short* vl = wsu + VLO + ib * 65536 + n;
            #pragma unroll
            for (int d = 0; d < 64; d++) {
                unsigned short h = f2us(av[d]);
                vh[d << 10] = h;
                vl[d << 10] = f2us(av[d] - us2f(h));
            }
        }
    } else {
        const int idx = blk - 64;
        const int b = idx >> 2;
        const int n = ((idx & 3) << 8) + t;
        if (fw) {
            const float* wqf = (const float*)wq; const float* bqf = (const float*)bq;
            for (int i = t; i < 2048; i += 256) sW[i] = wqf[i];
            if (t < 32) sW[2048 + t] = bqf[t];
        } else {
            const bf16* wqb = (const bf16*)wq; const bf16* bqb = (const bf16*)bq;
            for (int i = t; i < 2048; i += 256) sW[i] = b2f(wqb[i]);
            if (t < 32) sW[2048 + t] = b2f(bqb[t]);
        }
        __syncthreads();

        float aq[32];
        #pragma unroll
        for (int o = 0; o < 32; o++) aq[o] = sW[2048 + o];
        const int xoff = b * 65536 + n;
        if (fdyn) {
            const float* xp = (const float*)dyn + xoff;
            for (int c = 0; c < 64; c++) {
                float x = xp[c << 10];
                #pragma unroll
                for (int o = 0; o < 32; o++) aq[o] = fmaf(sW[(o << 6) + c], x, aq[o]);
            }
        } else {
            const bf16* xp = (const bf16*)dyn + xoff;
            for (int c = 0; c < 64; c++) {
                float x = b2f(xp[c << 10]);
                #pragma unroll
                for (int o = 0; o < 32; o++) aq[o] = fmaf(sW[(o << 6) + c], x, aq[o]);
            }
        }
        // qT[b][n][o] split-bf16
        unsigned short hs[32], ls[32];
        #pragma unroll
        for (int o = 0; o < 32; o++) {
            unsigned short h = f2us(aq[o]);
            hs[o] = h;
            ls[o] = f2us(aq[o] - us2f(h));
        }
        unsigned int* ph = ws32 + (QHI >> 1) + b * 16384 + n * 16;
        unsigned int* pl = ws32 + (QLO >> 1) + b * 16384 + n * 16;
        #pragma unroll
        for (int j = 0; j < 4; j++) {
            uint4 a, c;
            a.x = (unsigned)hs[j*8+0] | ((unsigned)hs[j*8+1] << 16);
            a.y = (unsigned)hs[j*8+2] | ((unsigned)hs[j*8+3] << 16);
            a.z = (unsigned)hs[j*8+4] | ((unsigned)hs[j*8+5] << 16);
            a.w = (unsigned)hs[j*8+6] | ((unsigned)hs[j*8+7] << 16);
            c.x = (unsigned)ls[j*8+0] | ((unsigned)ls[j*8+1] << 16);
            c.y = (unsigned)ls[j*8+2] | ((unsigned)ls[j*8+3] << 16);
            c.z = (unsigned)ls[j*8+4] | ((unsigned)ls[j*8+5] << 16);
            c.w = (unsigned)ls[j*8+6] | ((unsigned)ls[j*8+7] << 16);
            *reinterpret_cast<uint4*>(ph + j * 4) = a;
            *reinterpret_cast<uint4*>(pl + j * 4) = c;
        }
    }
}

// ---------------- Kernel 2: MFMA energy -> online softmax -> attn + out ----------------
// 1024 blocks x 256 threads. Each wave independently owns 16 q-rows: NO LDS, NO barriers.
// Swapped-operand energy: D = mfma(kT_frag, qT_frag) gives E[m][q] with q = lane&15,
// so each lane holds segments of ITS OWN attn row; a row-permuted K load makes each
// lane's 8 m-values contiguous -> P fragment feeds the out-GEMM A-operand directly.
// Split-bf16 (hi+lo, 3 MFMAs) keeps f32-level accuracy (product error ~2^-18).
__global__ __launch_bounds__(256) void attn_kernel(
    const unsigned short* __restrict__ wsu, const int* __restrict__ flags,
    void* __restrict__ dout)
{
    const int lane = threadIdx.x & 63;
    const int wid  = threadIdx.x >> 6;
    const int blk  = blockIdx.x;
    // XCD swizzle: all 16 blocks of a batch share one XCD's L2 (xcd = blk&7 heuristic)
    const int b  = ((blk & 7) << 3) | ((blk >> 3) & 7);       // 0..63
    const int qt = ((blk >> 6) << 2) + wid;                   // 0..63
    const int q0 = qt << 4;
    const int ib = ((b >> 5) << 3) + (b & 7);                 // xin batch
    const int g  = lane >> 4;
    const int r  = lane & 15;
    const int pr = ((r >> 2) << 3) + (r & 3);                 // row perm: {0-3,8-11,16-19,24-27}
    const int fo = flags[0] & flags[1] & flags[2];            // 1 = f32 output

    // q B-fragment (col = q0+r, k-dim o = 8g..8g+7), hi & lo — fixed for the whole wave
    const unsigned short* qp = wsu + QHI + ((size_t)b << 15) + ((q0 + r) << 5) + (g << 3);
    const s16x8 qh = *reinterpret_cast<const s16x8*>(qp);
    const s16x8 ql = *reinterpret_cast<const s16x8*>(qp + (QLO - QHI));

    const unsigned short* kb = wsu + KHI + ((size_t)ib << 15) + pr * 32 + (g << 3);
    const unsigned short* vb = wsu + VHI + ((size_t)ib << 16) + (r << 10) + (g << 3);

    const f32x4 z4 = {0.f, 0.f, 0.f, 0.f};

    // ---- pass 1: energy + per-lane online max/sum over this lane's m-subset ----
    float mx = -3.0e38f, sum = 0.f;
    #pragma unroll 2
    for (int ck = 0; ck < 32; ck++) {
        const unsigned short* ka = kb + (ck << 10);           // +32 rows * 32 o
        s16x8 kah = *reinterpret_cast<const s16x8*>(ka);
        s16x8 kal = *reinterpret_cast<const s16x8*>(ka + (KLO - KHI));
        s16x8 kbh = *reinterpret_cast<const s16x8*>(ka + 128);           // rows +4
        s16x8 kbl = *reinterpret_cast<const s16x8*>(ka + (KLO - KHI) + 128);
        f32x4 eA = mfma16(kah, qh, z4); eA = mfma16(kah, ql, eA); eA = mfma16(kal, qh, eA);
        f32x4 eB = mfma16(kbh, qh, z4); eB = mfma16(kbh, ql, eB); eB = mfma16(kbl, qh, eB);
        float t0 = fmaxf(fmaxf(fmaxf(eA[0], eA[1]), fmaxf(eA[2], eA[3])),
                         fmaxf(fmaxf(eB[0], eB[1]), fmaxf(eB[2], eB[3])));
        if (t0 > mx) { sum *= __expf(mx - t0); mx = t0; }
        sum += __expf(eA[0] - mx) + __expf(eA[1] - mx) + __expf(eA[2] - mx) + __expf(eA[3] - mx)
             + __expf(eB[0] - mx) + __expf(eB[1] - mx) + __expf(eB[2] - mx) + __expf(eB[3] - mx);
    }
    // combine the 4 lanes (xor 16, 32) sharing q-row r
    #pragma unroll
    for (int off = 16; off < 64; off <<= 1) {
        float mo = __shfl_xor(mx, off);
        float so = __shfl_xor(sum, off);
        float M  = fmaxf(mx, mo);
        sum = sum * __expf(mx - M) + so * __expf(mo - M);
        mx = M;
    }
    const float inv = 1.0f / sum;

    // ---- pass 2: recompute energy, normalize, write attn, accumulate out ----
    f32x4 acc[4] = { z4, z4, z4, z4 };
    float* attnF = (float*)dout + 4194304 + ((size_t)b << 20) + ((size_t)(q0 + r) << 10);
    bf16*  attnB = (bf16*)dout  + 4194304 + ((size_t)b << 20) + ((size_t)(q0 + r) << 10);

    #pragma unroll 2
    for (int ck = 0; ck < 32; ck++) {
        const unsigned short* ka = kb + (ck << 10);
        s16x8 kah = *reinterpret_cast<const s16x8*>(ka);
        s16x8 kal = *reinterpret_cast<const s16x8*>(ka + (KLO - KHI));
        s16x8 kbh = *reinterpret_cast<const s16x8*>(ka + 128);
        s16x8 kbl = *reinterpret_cast<const s16x8*>(ka + (KLO - KHI) + 128);
        f32x4 eA = mfma16(kah, qh, z4); eA = mfma16(kah, ql, eA); eA = mfma16(kal, qh, eA);
        f32x4 eB = mfma16(kbh, qh, z4); eB = mfma16(kbh, ql, eB); eB = mfma16(kbl, qh, eB);

        float p[8];
        #pragma unroll
        for (int j = 0; j < 4; j++) p[j]     = __expf(eA[j] - mx) * inv;
        #pragma unroll
        for (int j = 0; j < 4; j++) p[4 + j] = __expf(eB[j] - mx) * inv;

        s16x8 Ph, Pl;
        #pragma unroll
        for (int j = 0; j < 8; j++) {
            unsigned short h = f2us(p[j]);
            Ph[j] = (short)h;
            Pl[j] = (short)f2us(p[j] - us2f(h));
        }

        const int mo = (ck << 5) + (g << 3);                  // this lane's 8 contiguous m's
        if (fo) {
            f32x4 fa = { p[0], p[1], p[2], p[3] };
            f32x4 fb = { p[4], p[5], p[6], p[7] };
            __builtin_nontemporal_store(fa, reinterpret_cast<f32x4*>(attnF + mo));
            __builtin_nontemporal_store(fb, reinterpret_cast<f32x4*>(attnF + mo + 4));
        } else {
            __builtin_nontemporal_store(Ph, reinterpret_cast<s16x8*>(attnB + mo));
        }

        #pragma unroll
        for (int dt = 0; dt < 4; dt++) {
            const unsigned short* vp = vb + (dt << 14) + (ck << 5);
            s16x8 vh = *reinterpret_cast<const s16x8*>(vp);
            s16x8 vl = *reinterpret_cast<const s16x8*>(vp + (VLO - VHI));
            acc[dt] = mfma16(Ph, vh, acc[dt]);
            acc[dt] = mfma16(Ph, vl, acc[dt]);
            acc[dt] = mfma16(Pl, vh, acc[dt]);
        }
    }

    // out[b][d][qrow]: D layout -> lane writes float4 at (d = dt*16+r, qrow = q0+4g..+3)
    if (fo) {
        float* ob = (float*)dout + ((size_t)b << 16) + (r << 10) + q0 + (g << 2);
        #pragma unroll
        for (int dt = 0; dt < 4; dt++) {
            f32x4 f = { acc[dt][0], acc[dt][1], acc[dt][2], acc[dt][3] };
            __builtin_nontemporal_store(f, reinterpret_cast<f32x4*>(ob + (dt << 14)));
        }
    } else {
        bf16* ob = (bf16*)dout + ((size_t)b << 16) + (r << 10) + q0 + (g << 2);
        #pragma unroll
        for (int dt = 0; dt < 4; dt++) {
            ushort4 u;
            u.x = f2us(acc[dt][0]); u.y = f2us(acc[dt][1]);
            u.z = f2us(acc[dt][2]); u.w = f2us(acc[dt][3]);
            *reinterpret_cast<ushort4*>(ob + (dt << 14)) = u;
        }
    }
}

extern "C" void kernel_launch(void* const* d_in, const int* in_sizes, int n_in,
                              void* d_out, int out_size, void* d_ws, size_t ws_size,
                              hipStream_t stream) {
    unsigned short* wsu = (unsigned short*)d_ws;
    int* flags = (int*)((char*)d_ws + FLG_BYTE);

    detect_kernel<<<3, 256, 0, stream>>>(d_in[0], d_in[1], d_in[2], flags);
    proj_kernel<<<320, 256, 0, stream>>>(d_in[0], d_in[1], d_in[2], d_in[3],
                                         d_in[4], d_in[5], d_in[6], d_in[7],
                                         wsu, flags);
    attn_kernel<<<1024, 256, 0, stream>>>(wsu, flags, d_out);
}

// Round 4
// 415.178 us; speedup vs baseline: 2.2802x; 1.3022x over previous
//
#include <hip/hip_runtime.h>
#include <hip/hip_bf16.h>

typedef __hip_bfloat16 bf16;
typedef float f32x4 __attribute__((ext_vector_type(4)));
typedef short s16x8 __attribute__((ext_vector_type(8)));

static __device__ __forceinline__ float b2f(bf16 h) { return __bfloat162float(h); }
static __device__ __forceinline__ float us2f(unsigned short u) {
    union { unsigned short u; bf16 h; } cv; cv.u = u; return __bfloat162float(cv.h);
}
static __device__ __forceinline__ unsigned short f2us(float f) {
    __hip_bfloat16 h = __float2bfloat16(f);
    union { __hip_bfloat16 h; unsigned short u; } cv; cv.h = h; return cv.u;
}
// split x = hi + lo; hi = RTNE bf16 (bit-identical to prior rounds), lo = truncated bf16
static __device__ __forceinline__ void split2(float x, unsigned short& h, unsigned short& l) {
    unsigned short hh = f2us(x);
    float lo = x - us2f(hh);
    union { float f; unsigned u; } cv; cv.f = lo;
    h = hh;
    l = (unsigned short)(cv.u >> 16);
}

#define LOG2E 1.4426950408889634f

// ws layout (ushort elements). Split-bf16 planes: x = hi + lo (each bf16).
//   qT hi: [64 b][1024 n][32 o]   at 0          (2,097,152)   NOTE: q pre-scaled by log2(e)
//   qT lo:                        at 2,097,152
//   kT hi: [16 ib][1024 m][32 o]  at 4,194,304  (  524,288)
//   kT lo:                        at 4,718,592
//   v  hi: [16 ib][64 d][1024 m]  at 5,242,880  (1,048,576)
//   v  lo:                        at 6,291,456
//   flags (int[4])                at byte 14,680,064
#define QHI 0
#define QLO 2097152
#define KHI 4194304
#define KLO 4718592
#define VHI 5242880
#define VLO 6291456
#define FLG_BYTE 14680064

static __device__ __forceinline__ f32x4 mfma16(s16x8 a, s16x8 b, f32x4 c) {
    return __builtin_amdgcn_mfma_f32_16x16x32_bf16(a, b, c, 0, 0, 0);
}

// ---------------- Kernel 0: dtype detection (unchanged) ----------------
__global__ __launch_bounds__(256) void detect_kernel(
    const void* inp, const void* dyn, const void* wq, int* flags)
{
    __shared__ int bad;
    if (threadIdx.x == 0) bad = 0;
    __syncthreads();
    const void* bufs[3] = { inp, dyn, wq };
    const int nscan[3] = { 2048, 2048, 1024 };
    const int b = blockIdx.x;
    const unsigned short* u = (const unsigned short*)bufs[b];
    int myBad = 0;
    for (int i = threadIdx.x; i < nscan[b]; i += 256) {
        float x = us2f(u[i * 2]);
        if (!(x > -1e4f && x < 1e4f)) myBad++;
    }
    atomicAdd(&bad, myBad);
    __syncthreads();
    if (threadIdx.x == 0) flags[b] = (bad >= 4) ? 1 : 0;
}

// ---------------- Kernel 1: projections -> split-bf16 transposed planes ----------------
// blocks 0..255    : k+v. blk>>4 = ib (16), blk&15 = 64-n group. thread: n = t&63, og = t>>6.
//                    og splits the 96 outputs (32 k + 64 v) into 4 groups of 24. No reduction.
// blocks 256..1279 : q. (blk-256)>>4 = b (64), &15 = n group. og splits 32 o into 4 groups of 8.
// Weights staged once in LDS as unified sW[96][64] (k rows 0..31, v rows 32..95), read as float4.
__global__ __launch_bounds__(256) void proj_kernel(
    const void* __restrict__ inputs, const void* __restrict__ dyn,
    const void* __restrict__ wq, const void* __restrict__ bq,
    const void* __restrict__ wk, const void* __restrict__ bk,
    const void* __restrict__ wv, const void* __restrict__ bv,
    unsigned short* __restrict__ wsu, const int* __restrict__ flags)
{
    __shared__ float sW[6144];
    __shared__ float sB[96];
    const int t   = threadIdx.x;
    const int blk = blockIdx.x;
    const int fin = flags[0];
    const int fdyn = flags[1];
    const int fw  = flags[2];
    const int nl  = t & 63;
    const int og  = t >> 6;          // wave-uniform
    unsigned int* ws32 = (unsigned int*)wsu;
    const float4* sW4 = (const float4*)sW;

    if (blk < 256) {
        const int ib = blk >> 4;
        const int n  = ((blk & 15) << 6) + nl;
        if (fw) {
            const float* wkf = (const float*)wk; const float* wvf = (const float*)wv;
            for (int i = t; i < 2048; i += 256) sW[i] = wkf[i];
            for (int i = t; i < 4096; i += 256) sW[2048 + i] = wvf[i];
            if (t < 32) sB[t] = ((const float*)bk)[t];
            else if (t >= 64 && t < 128) sB[32 + t - 64] = ((const float*)bv)[t - 64];
        } else {
            const bf16* wkb = (const bf16*)wk; const bf16* wvb = (const bf16*)wv;
            for (int i = t; i < 2048; i += 256) sW[i] = b2f(wkb[i]);
            for (int i = t; i < 4096; i += 256) sW[2048 + i] = b2f(wvb[i]);
            if (t < 32) sB[t] = b2f(((const bf16*)bk)[t]);
            else if (t >= 64 && t < 128) sB[32 + t - 64] = b2f(((const bf16*)bv)[t - 64]);
        }
        __syncthreads();

        const int o0 = og * 24;
        float acc[24];
        #pragma unroll
        for (int j = 0; j < 24; j++) acc[j] = sB[o0 + j];

        if (fin) {
            const float* xp = (const float*)inputs + ib * 65536 + n;
            for (int c4 = 0; c4 < 16; c4++) {
                float x0 = xp[(c4 * 4 + 0) << 10];
                float x1 = xp[(c4 * 4 + 1) << 10];
                float x2 = xp[(c4 * 4 + 2) << 10];
                float x3 = xp[(c4 * 4 + 3) << 10];
                #pragma unroll
                for (int j = 0; j < 24; j++) {
                    float4 w = sW4[(o0 + j) * 16 + c4];
                    acc[j] = fmaf(w.x, x0, fmaf(w.y, x1, fmaf(w.z, x2, fmaf(w.w, x3, acc[j]))));
                }
            }
        } else {
            const bf16* xp = (const bf16*)inputs + ib * 65536 + n;
            for (int c4 = 0; c4 < 16; c4++) {
                float x0 = b2f(xp[(c4 * 4 + 0) << 10]);
                float x1 = b2f(xp[(c4 * 4 + 1) << 10]);
                float x2 = b2f(xp[(c4 * 4 + 2) << 10]);
                float x3 = b2f(xp[(c4 * 4 + 3) << 10]);
                #pragma unroll
                for (int j = 0; j < 24; j++) {
                    float4 w = sW4[(o0 + j) * 16 + c4];
                    acc[j] = fmaf(w.x, x0, fmaf(w.y, x1, fmaf(w.z, x2, fmaf(w.w, x3, acc[j]))));
                }
            }
        }

        // k chunks of 8 (og0: outs 0..23; og1: outs 24..31)
        #define STORE_KCHUNK(JB)                                                    \
        {                                                                           \
            unsigned short hs[8], ls[8];                                            \
            _Pragma("unroll")                                                       \
            for (int j2 = 0; j2 < 8; j2++) split2(acc[(JB) + j2], hs[j2], ls[j2]);  \
            uint4 A, C;                                                             \
            A.x = (unsigned)hs[0] | ((unsigned)hs[1] << 16);                        \
            A.y = (unsigned)hs[2] | ((unsigned)hs[3] << 16);                        \
            A.z = (unsigned)hs[4] | ((unsigned)hs[5] << 16);                        \
            A.w = (unsigned)hs[6] | ((unsigned)hs[7] << 16);                        \
            C.x = (unsigned)ls[0] | ((unsigned)ls[1] << 16);                        \
            C.y = (unsigned)ls[2] | ((unsigned)ls[3] << 16);                        \
            C.z = (unsigned)ls[4] | ((unsigned)ls[5] << 16);                        \
            C.w = (unsigned)ls[6] | ((unsigned)ls[7] << 16);                        \
            unsigned int* ph = ws32 + (KHI >> 1) + ib * 16384 + n * 16 + ((o0 + (JB)) >> 1); \
            *reinterpret_cast<uint4*>(ph) = A;                                      \
            *reinterpret_cast<uint4*>(ph + ((KLO - KHI) >> 1)) = C;                 \
        }
        if (og == 0) { STORE_KCHUNK(0); STORE_KCHUNK(8); STORE_KCHUNK(16); }
        else if (og == 1) { STORE_KCHUNK(0); }
        #undef STORE_KCHUNK

        // v part: oi >= 32 -> d = oi-32, store [d][n] scalar (coalesced over n)
        unsigned short* vh = wsu + VHI + ib * 65536 + n;
        unsigned short* vl = wsu + VLO + ib * 65536 + n;
        #pragma unroll
        for (int j = 0; j < 24; j++) {
            const int oi = o0 + j;
            if (oi >= 32) {
                const int d = oi - 32;
                unsigned short h, l; split2(acc[j], h, l);
                vh[d << 10] = h;
                vl[d << 10] = l;
            }
        }
    } else {
        const int qb = blk - 256;
        const int bb = qb >> 4;
        const int n  = ((qb & 15) << 6) + nl;
        if (fw) {
            const float* wqf = (const float*)wq;
            for (int i = t; i < 2048; i += 256) sW[i] = wqf[i] * LOG2E;
            if (t < 32) sB[t] = ((const float*)bq)[t] * LOG2E;
        } else {
            const bf16* wqb = (const bf16*)wq;
            for (int i = t; i < 2048; i += 256) sW[i] = b2f(wqb[i]) * LOG2E;
            if (t < 32) sB[t] = b2f(((const bf16*)bq)[t]) * LOG2E;
        }
        __syncthreads();

        const int o0 = og * 8;
        float acc[8];
        #pragma unroll
        for (int j = 0; j < 8; j++) acc[j] = sB[o0 + j];

        if (fdyn) {
            const float* xp = (const float*)dyn + bb * 65536 + n;
            for (int c4 = 0; c4 < 16; c4++) {
                float x0 = xp[(c4 * 4 + 0) << 10];
                float x1 = xp[(c4 * 4 + 1) << 10];
                float x2 = xp[(c4 * 4 + 2) << 10];
                float x3 = xp[(c4 * 4 + 3) << 10];
                #pragma unroll
                for (int j = 0; j < 8; j++) {
                    float4 w = sW4[(o0 + j) * 16 + c4];
                    acc[j] = fmaf(w.x, x0, fmaf(w.y, x1, fmaf(w.z, x2, fmaf(w.w, x3, acc[j]))));
                }
            }
        } else {
            const bf16* xp = (const bf16*)dyn + bb * 65536 + n;
            for (int c4 = 0; c4 < 16; c4++) {
                float x0 = b2f(xp[(c4 * 4 + 0) << 10]);
                float x1 = b2f(xp[(c4 * 4 + 1) << 10]);
                float x2 = b2f(xp[(c4 * 4 + 2) << 10]);
                float x3 = b2f(xp[(c4 * 4 + 3) << 10]);
                #pragma unroll
                for (int j = 0; j < 8; j++) {
                    float4 w = sW4[(o0 + j) * 16 + c4];
                    acc[j] = fmaf(w.x, x0, fmaf(w.y, x1, fmaf(w.z, x2, fmaf(w.w, x3, acc[j]))));
                }
            }
        }

        unsigned short hs[8], ls[8];
        #pragma unroll
        for (int j = 0; j < 8; j++) split2(acc[j], hs[j], ls[j]);
        uint4 A, C;
        A.x = (unsigned)hs[0] | ((unsigned)hs[1] << 16);
        A.y = (unsigned)hs[2] | ((unsigned)hs[3] << 16);
        A.z = (unsigned)hs[4] | ((unsigned)hs[5] << 16);
        A.w = (unsigned)hs[6] | ((unsigned)hs[7] << 16);
        C.x = (unsigned)ls[0] | ((unsigned)ls[1] << 16);
        C.y = (unsigned)ls[2] | ((unsigned)ls[3] << 16);
        C.z = (unsigned)ls[4] | ((unsigned)ls[5] << 16);
        C.w = (unsigned)ls[6] | ((unsigned)ls[7] << 16);
        unsigned int* ph = ws32 + (QHI >> 1) + bb * 16384 + n * 16 + (o0 >> 1);
        *reinterpret_cast<uint4*>(ph) = A;
        *reinterpret_cast<uint4*>(ph + ((QLO - QHI) >> 1)) = C;
    }
}

// ---------------- Kernel 2: MFMA energy -> online softmax -> attn + out ----------------
// 512 blocks x 256 threads, no LDS, no barriers. Each wave owns TWO 16-row q-tiles
// (rows q0..q0+31) sharing every K and V fragment load; K is prefetched one ck ahead.
// q was pre-scaled by log2(e) at projection so all exponentials are raw exp2f.
__global__ __launch_bounds__(256) void attn_kernel(
    const unsigned short* __restrict__ wsu, const int* __restrict__ flags,
    void* __restrict__ dout)
{
    const int lane = threadIdx.x & 63;
    const int wid  = threadIdx.x >> 6;
    const int blk  = blockIdx.x;
    const int b    = blk >> 3;                                // 0..63
    const int pair = ((blk & 7) << 2) + wid;                  // 0..31
    const int q0   = pair << 5;                               // 32 rows per wave
    const int ib   = ((b >> 5) << 3) + (b & 7);               // xin batch
    const int g    = lane >> 4;
    const int r    = lane & 15;
    const int pr   = ((r >> 2) << 3) + (r & 3);
    const int fo   = flags[0] & flags[1] & flags[2];          // 1 = f32 output

    const unsigned short* qp0 = wsu + QHI + ((size_t)b << 15) + ((q0 + r) << 5) + (g << 3);
    const s16x8 qh0 = *reinterpret_cast<const s16x8*>(qp0);
    const s16x8 ql0 = *reinterpret_cast<const s16x8*>(qp0 + (QLO - QHI));
    const s16x8 qh1 = *reinterpret_cast<const s16x8*>(qp0 + 512);
    const s16x8 ql1 = *reinterpret_cast<const s16x8*>(qp0 + (QLO - QHI) + 512);

    const unsigned short* kb = wsu + KHI + ((size_t)ib << 15) + pr * 32 + (g << 3);
    const unsigned short* vb = wsu + VHI + ((size_t)ib << 16) + (r << 10) + (g << 3);

    const f32x4 z4 = {0.f, 0.f, 0.f, 0.f};

    // ---- pass 1: energy + per-lane online max/sum, both tiles, K prefetched ----
    float mx0 = -3.0e38f, sm0 = 0.f, mx1 = -3.0e38f, sm1 = 0.f;
    s16x8 kah = *reinterpret_cast<const s16x8*>(kb);
    s16x8 kal = *reinterpret_cast<const s16x8*>(kb + (KLO - KHI));
    s16x8 kbh = *reinterpret_cast<const s16x8*>(kb + 128);
    s16x8 kbl = *reinterpret_cast<const s16x8*>(kb + (KLO - KHI) + 128);
    #pragma unroll 2
    for (int ck = 0; ck < 32; ck++) {
        const unsigned short* kn = kb + ((ck < 31 ? ck + 1 : 31) << 10);
        s16x8 nah = *reinterpret_cast<const s16x8*>(kn);
        s16x8 nal = *reinterpret_cast<const s16x8*>(kn + (KLO - KHI));
        s16x8 nbh = *reinterpret_cast<const s16x8*>(kn + 128);
        s16x8 nbl = *reinterpret_cast<const s16x8*>(kn + (KLO - KHI) + 128);

        f32x4 eA0 = mfma16(kah, qh0, z4); eA0 = mfma16(kah, ql0, eA0); eA0 = mfma16(kal, qh0, eA0);
        f32x4 eB0 = mfma16(kbh, qh0, z4); eB0 = mfma16(kbh, ql0, eB0); eB0 = mfma16(kbl, qh0, eB0);
        f32x4 eA1 = mfma16(kah, qh1, z4); eA1 = mfma16(kah, ql1, eA1); eA1 = mfma16(kal, qh1, eA1);
        f32x4 eB1 = mfma16(kbh, qh1, z4); eB1 = mfma16(kbh, ql1, eB1); eB1 = mfma16(kbl, qh1, eB1);

        float t0 = fmaxf(fmaxf(fmaxf(eA0[0], eA0[1]), fmaxf(eA0[2], eA0[3])),
                         fmaxf(fmaxf(eB0[0], eB0[1]), fmaxf(eB0[2], eB0[3])));
        if (t0 > mx0) { sm0 *= exp2f(mx0 - t0); mx0 = t0; }
        sm0 += exp2f(eA0[0]-mx0) + exp2f(eA0[1]-mx0) + exp2f(eA0[2]-mx0) + exp2f(eA0[3]-mx0)
             + exp2f(eB0[0]-mx0) + exp2f(eB0[1]-mx0) + exp2f(eB0[2]-mx0) + exp2f(eB0[3]-mx0);

        float t1 = fmaxf(fmaxf(fmaxf(eA1[0], eA1[1]), fmaxf(eA1[2], eA1[3])),
                         fmaxf(fmaxf(eB1[0], eB1[1]), fmaxf(eB1[2], eB1[3])));
        if (t1 > mx1) { sm1 *= exp2f(mx1 - t1); mx1 = t1; }
        sm1 += exp2f(eA1[0]-mx1) + exp2f(eA1[1]-mx1) + exp2f(eA1[2]-mx1) + exp2f(eA1[3]-mx1)
             + exp2f(eB1[0]-mx1) + exp2f(eB1[1]-mx1) + exp2f(eB1[2]-mx1) + exp2f(eB1[3]-mx1);

        kah = nah; kal = nal; kbh = nbh; kbl = nbl;
    }
    // combine the 4 lanes (xor 16, 32) sharing each q-row
    #pragma unroll
    for (int off = 16; off < 64; off <<= 1) {
        float mo0 = __shfl_xor(mx0, off), so0 = __shfl_xor(sm0, off);
        float M0 = fmaxf(mx0, mo0);
        sm0 = sm0 * exp2f(mx0 - M0) + so0 * exp2f(mo0 - M0); mx0 = M0;
        float mo1 = __shfl_xor(mx1, off), so1 = __shfl_xor(sm1, off);
        float M1 = fmaxf(mx1, mo1);
        sm1 = sm1 * exp2f(mx1 - M1) + so1 * exp2f(mo1 - M1); mx1 = M1;
    }
    const float inv0 = 1.0f / sm0;
    const float inv1 = 1.0f / sm1;

    // ---- pass 2: recompute energy, normalize, write attn, accumulate out ----
    f32x4 a0[4] = { z4, z4, z4, z4 };
    f32x4 a1[4] = { z4, z4, z4, z4 };
    float* attnF0 = (float*)dout + 4194304 + ((size_t)b << 20) + ((size_t)(q0 + r) << 10);
    bf16*  attnB0 = (bf16*)dout  + 4194304 + ((size_t)b << 20) + ((size_t)(q0 + r) << 10);
    float* attnF1 = attnF0 + 16384;
    bf16*  attnB1 = attnB0 + 16384;

    kah = *reinterpret_cast<const s16x8*>(kb);
    kal = *reinterpret_cast<const s16x8*>(kb + (KLO - KHI));
    kbh = *reinterpret_cast<const s16x8*>(kb + 128);
    kbl = *reinterpret_cast<const s16x8*>(kb + (KLO - KHI) + 128);
    for (int ck = 0; ck < 32; ck++) {
        const unsigned short* kn = kb + ((ck < 31 ? ck + 1 : 31) << 10);
        s16x8 nah = *reinterpret_cast<const s16x8*>(kn);
        s16x8 nal = *reinterpret_cast<const s16x8*>(kn + (KLO - KHI));
        s16x8 nbh = *reinterpret_cast<const s16x8*>(kn + 128);
        s16x8 nbl = *reinterpret_cast<const s16x8*>(kn + (KLO - KHI) + 128);

        const unsigned short* vp = vb + (ck << 5);
        s16x8 vh[4], vl[4];
        #pragma unroll
        for (int dt = 0; dt < 4; dt++) {
            vh[dt] = *reinterpret_cast<const s16x8*>(vp + (dt << 14));
            vl[dt] = *reinterpret_cast<const s16x8*>(vp + (VLO - VHI) + (dt << 14));
        }

        f32x4 eA0 = mfma16(kah, qh0, z4); eA0 = mfma16(kah, ql0, eA0); eA0 = mfma16(kal, qh0, eA0);
        f32x4 eB0 = mfma16(kbh, qh0, z4); eB0 = mfma16(kbh, ql0, eB0); eB0 = mfma16(kbl, qh0, eB0);
        f32x4 eA1 = mfma16(kah, qh1, z4); eA1 = mfma16(kah, ql1, eA1); eA1 = mfma16(kal, qh1, eA1);
        f32x4 eB1 = mfma16(kbh, qh1, z4); eB1 = mfma16(kbh, ql1, eB1); eB1 = mfma16(kbl, qh1, eB1);

        float p0[8], p1[8];
        #pragma unroll
        for (int j = 0; j < 4; j++) { p0[j] = exp2f(eA0[j] - mx0) * inv0; p0[4+j] = exp2f(eB0[j] - mx0) * inv0; }
        #pragma unroll
        for (int j = 0; j < 4; j++) { p1[j] = exp2f(eA1[j] - mx1) * inv1; p1[4+j] = exp2f(eB1[j] - mx1) * inv1; }

        s16x8 Ph0, Pl0, Ph1, Pl1;
        #pragma unroll
        for (int j = 0; j < 8; j++) {
            unsigned short h, l;
            split2(p0[j], h, l); Ph0[j] = (short)h; Pl0[j] = (short)l;
            split2(p1[j], h, l); Ph1[j] = (short)h; Pl1[j] = (short)l;
        }

        const int mo = (ck << 5) + (g << 3);
        if (fo) {
            f32x4 fa0 = { p0[0], p0[1], p0[2], p0[3] };
            f32x4 fb0 = { p0[4], p0[5], p0[6], p0[7] };
            f32x4 fa1 = { p1[0], p1[1], p1[2], p1[3] };
            f32x4 fb1 = { p1[4], p1[5], p1[6], p1[7] };
            *reinterpret_cast<f32x4*>(attnF0 + mo)     = fa0;
            *reinterpret_cast<f32x4*>(attnF0 + mo + 4) = fb0;
            *reinterpret_cast<f32x4*>(attnF1 + mo)     = fa1;
            *reinterpret_cast<f32x4*>(attnF1 + mo + 4) = fb1;
        } else {
            *reinterpret_cast<s16x8*>(attnB0 + mo) = Ph0;
            *reinterpret_cast<s16x8*>(attnB1 + mo) = Ph1;
        }

        __builtin_amdgcn_s_setprio(1);
        #pragma unroll
        for (int dt = 0; dt < 4; dt++) {
            a0[dt] = mfma16(Ph0, vh[dt], a0[dt]);
            a0[dt] = mfma16(Ph0, vl[dt], a0[dt]);
            a0[dt] = mfma16(Pl0, vh[dt], a0[dt]);
            a1[dt] = mfma16(Ph1, vh[dt], a1[dt]);
            a1[dt] = mfma16(Ph1, vl[dt], a1[dt]);
            a1[dt] = mfma16(Pl1, vh[dt], a1[dt]);
        }
        __builtin_amdgcn_s_setprio(0);

        kah = nah; kal = nal; kbh = nbh; kbl = nbl;
    }

    // out[b][d][qrow]: lane writes 4 consecutive qrows at (d = dt*16 + r, qrow = q0(+16) + 4g..)
    if (fo) {
        float* ob = (float*)dout + ((size_t)b << 16) + (r << 10) + q0 + (g << 2);
        #pragma unroll
        for (int dt = 0; dt < 4; dt++) {
            f32x4 f0 = { a0[dt][0], a0[dt][1], a0[dt][2], a0[dt][3] };
            f32x4 f1 = { a1[dt][0], a1[dt][1], a1[dt][2], a1[dt][3] };
            *reinterpret_cast<f32x4*>(ob + (dt << 14))      = f0;
            *reinterpret_cast<f32x4*>(ob + (dt << 14) + 16) = f1;
        }
    } else {
        bf16* ob = (bf16*)dout + ((size_t)b << 16) + (r << 10) + q0 + (g << 2);
        #pragma unroll
        for (int dt = 0; dt < 4; dt++) {
            ushort4 u0, u1;
            u0.x = f2us(a0[dt][0]); u0.y = f2us(a0[dt][1]); u0.z = f2us(a0[dt][2]); u0.w = f2us(a0[dt][3]);
            u1.x = f2us(a1[dt][0]); u1.y = f2us(a1[dt][1]); u1.z = f2us(a1[dt][2]); u1.w = f2us(a1[dt][3]);
            *reinterpret_cast<ushort4*>(ob + (dt << 14))      = u0;
            *reinterpret_cast<ushort4*>(ob + (dt << 14) + 16) = u1;
        }
    }
}

extern "C" void kernel_launch(void* const* d_in, const int* in_sizes, int n_in,
                              void* d_out, int out_size, void* d_ws, size_t ws_size,
                              hipStream_t stream) {
    unsigned short* wsu = (unsigned short*)d_ws;
    int* flags = (int*)((char*)d_ws + FLG_BYTE);

    detect_kernel<<<3, 256, 0, stream>>>(d_in[0], d_in[1], d_in[2], flags);
    proj_kernel<<<1280, 256, 0, stream>>>(d_in[0], d_in[1], d_in[2], d_in[3],
                                          d_in[4], d_in[5], d_in[6], d_in[7],
                                          wsu, flags);
    attn_kernel<<<512, 256, 0, stream>>>(wsu, flags, d_out);
}